// Round 5
// baseline (474.081 us; speedup 1.0000x reference)
//
#include <hip/hip_runtime.h>

#define N_NODES 100000
#define N_EDGES 640000
#define IN_DIM  128
#define OUT_DIM 128
#define N_REL   16
#define EPB     64
#define PAD     1024                     // relation-padding slop (16*63 rounded up)
#define NB_SCAN ((N_NODES + 255) / 256)
#define CVT_XB  (N_NODES * IN_DIM / 4 / 256)   // 12500 blocks for x
#define CVT_WB  (17 * 16384 / 256)             // 1088 blocks for W

typedef unsigned short u16;
typedef unsigned int   u32;
typedef __attribute__((ext_vector_type(8))) short bf16x8;
typedef __attribute__((ext_vector_type(4))) float f32x4;

__device__ inline u16 f2bf(float f) {               // round-to-nearest-even
    u32 u = __builtin_bit_cast(u32, f);
    return (u16)((u + 0x7fffu + ((u >> 16) & 1u)) >> 16);
}
__device__ inline float bf2f(u16 s) {
    u32 u = ((u32)s) << 16;
    return __builtin_bit_cast(float, u);
}

// ---------------- fused dtype conversion (x and W) ----------------
__global__ __launch_bounds__(256) void k_cvt(const float* __restrict__ x,
                                             const float* __restrict__ rw,
                                             const float* __restrict__ sw,
                                             u16* __restrict__ xb,
                                             u16* __restrict__ wt) {
    int b = blockIdx.x, t = threadIdx.x;
    if (b < CVT_XB) {
        int i = b * 256 + t;
        float4 v = ((const float4*)x)[i];
        ushort4 p; p.x = f2bf(v.x); p.y = f2bf(v.y); p.z = f2bf(v.z); p.w = f2bf(v.w);
        ((ushort4*)xb)[i] = p;
    } else {
        int i = (b - CVT_XB) * 256 + t;     // over 17*16384, exact
        int r = i >> 14, rem = i & 16383, n = rem & 127;
        float v = (r < 16) ? rw[i] : sw[rem];
        int k = rem >> 7;
        wt[(size_t)r * 16384 + n * 128 + k] = f2bf(v);
    }
}

// ---------------- histograms ----------------
__global__ __launch_bounds__(256) void k_hist(const int* __restrict__ etype,
                                              const int* __restrict__ dst,
                                              int* __restrict__ counts_rel,
                                              int* __restrict__ dst_count) {
    __shared__ int bins[N_REL];
    int t = threadIdx.x;
    if (t < N_REL) bins[t] = 0;
    __syncthreads();
    int e = blockIdx.x * 256 + t;
    if (e < N_EDGES) {
        atomicAdd(&bins[etype[e]], 1);
        atomicAdd(&dst_count[dst[e]], 1);
    }
    __syncthreads();
    if (t < N_REL && bins[t]) atomicAdd(&counts_rel[t], bins[t]);
}

__global__ __launch_bounds__(256) void k_hist_rel(const int* __restrict__ etype,
                                                  int* __restrict__ counts_rel) {
    __shared__ int bins[N_REL];
    int t = threadIdx.x;
    if (t < N_REL) bins[t] = 0;
    __syncthreads();
    int e = blockIdx.x * 256 + t;
    if (e < N_EDGES) atomicAdd(&bins[etype[e]], 1);
    __syncthreads();
    if (t < N_REL && bins[t]) atomicAdd(&counts_rel[t], bins[t]);
}

// padded (to 64) segment starts; seg[16] = E_pad
__global__ void k_scan_rel_pad(const int* __restrict__ counts, int* __restrict__ cursor,
                               int* __restrict__ seg) {
    if (threadIdx.x == 0) {
        int s = 0;
        for (int r = 0; r < N_REL; ++r) {
            cursor[r] = s; seg[r] = s;
            s += (counts[r] + 63) & ~63;
        }
        seg[N_REL] = s;
    }
}

__global__ void k_scan_rel(const int* __restrict__ counts, int* __restrict__ cursor) {
    if (threadIdx.x == 0) {
        int s = 0;
        for (int r = 0; r < N_REL; ++r) { cursor[r] = s; s += counts[r]; }
    }
}

// fill padding slots with sentinel N_EDGES + r (encodes relation)
__global__ __launch_bounds__(256) void k_fill(const int* __restrict__ counts,
                                              const int* __restrict__ seg,
                                              int* __restrict__ sorted) {
    int t = threadIdx.x;
    for (int r = 0; r < N_REL; ++r) {
        int b = seg[r] + counts[r], e2 = seg[r + 1];
        if (b + t < e2) sorted[b + t] = N_EDGES + r;   // pad < 64 per segment
    }
    for (int i = seg[N_REL] + t; i < N_EDGES + PAD; i += 256)
        sorted[i] = N_EDGES + (N_REL - 1);
}

// relation counting-sort + dst-grouped position, fused
__global__ __launch_bounds__(256) void k_scatter_pos(const int* __restrict__ etype,
                                                     const int* __restrict__ dst,
                                                     int* __restrict__ cursor_rel,
                                                     int* __restrict__ cursor_dst,
                                                     int* __restrict__ sorted,
                                                     int* __restrict__ pos) {
    __shared__ int bins[N_REL];
    __shared__ int base[N_REL];
    int t = threadIdx.x;
    if (t < N_REL) bins[t] = 0;
    __syncthreads();
    int e = blockIdx.x * 256 + t;
    int rel = 0;
    bool valid = (e < N_EDGES);
    if (valid) { rel = etype[e]; atomicAdd(&bins[rel], 1); }
    __syncthreads();
    if (t < N_REL) {
        base[t] = bins[t] ? atomicAdd(&cursor_rel[t], bins[t]) : 0;
        bins[t] = 0;
    }
    __syncthreads();
    if (valid) {
        int slot = base[rel] + atomicAdd(&bins[rel], 1);
        sorted[slot] = e;
        pos[slot] = atomicAdd(&cursor_dst[dst[e]], 1);
    }
}

// ---------------- exclusive scan over dst_count -> row_ptr ----------------
__global__ __launch_bounds__(256) void k_scan1(const int* __restrict__ dst_count,
                                               int* __restrict__ row_ptr,
                                               int* __restrict__ part) {
    __shared__ int buf[2][256];
    int t = threadIdx.x;
    int i = blockIdx.x * 256 + t;
    int v = (i < N_NODES) ? dst_count[i] : 0;
    buf[0][t] = v;
    __syncthreads();
    int cur = 0;
    #pragma unroll
    for (int off = 1; off < 256; off <<= 1) {
        int nxt = cur ^ 1;
        int s = buf[cur][t];
        if (t >= off) s += buf[cur][t - off];
        buf[nxt][t] = s;
        __syncthreads();
        cur = nxt;
    }
    int inc = buf[cur][t];
    if (i < N_NODES) row_ptr[i] = inc - v;
    if (t == 255) part[blockIdx.x] = inc;
}

__global__ __launch_bounds__(512) void k_scan2(int* __restrict__ part) {
    __shared__ int buf[2][512];
    int t = threadIdx.x;
    int v = (t < NB_SCAN) ? part[t] : 0;
    buf[0][t] = v;
    __syncthreads();
    int cur = 0;
    #pragma unroll
    for (int off = 1; off < 512; off <<= 1) {
        int nxt = cur ^ 1;
        int s = buf[cur][t];
        if (t >= off) s += buf[cur][t - off];
        buf[nxt][t] = s;
        __syncthreads();
        cur = nxt;
    }
    int inc = buf[cur][t];
    if (t < NB_SCAN) part[t] = inc - v;
}

__global__ __launch_bounds__(256) void k_scan3(int* __restrict__ row_ptr,
                                               const int* __restrict__ part,
                                               int* __restrict__ cursor_dst) {
    int t = threadIdx.x;
    int i = blockIdx.x * 256 + t;
    if (i < N_NODES) {
        int r = row_ptr[i] + part[blockIdx.x];
        row_ptr[i] = r;
        cursor_dst[i] = r;
    }
    if (i == 0) row_ptr[N_NODES] = N_EDGES;
}

// ---------------- self transform (MFMA, LDS-free) ----------------
__global__ __launch_bounds__(256, 4) void k_self_mfma(const u16* __restrict__ xb,
                                                      const u16* __restrict__ wt,
                                                      const float* __restrict__ bias,
                                                      float* __restrict__ out) {
    int t = threadIdx.x;
    int w = t >> 6, lane = t & 63;
    int n = lane & 15, q = lane >> 4;
    int n0 = blockIdx.x * 256 + w * 64;
    const u16* wr = wt + (size_t)16 * 16384;     // self weight = "relation 16"

    bf16x8 bx[4][4];
    int node[4];
    #pragma unroll
    for (int g = 0; g < 4; ++g) {
        node[g] = n0 + g * 16 + n;
        int rn = node[g] < N_NODES ? node[g] : N_NODES - 1;
        const u16* xrow = xb + (size_t)rn * 128 + q * 8;
        #pragma unroll
        for (int kk = 0; kk < 4; ++kk)
            bx[g][kk] = *(const bf16x8*)(xrow + kk * 32);
    }
    #pragma unroll
    for (int c = 0; c < 8; ++c) {
        bf16x8 aw[4];
        const u16* wrow = wr + (c * 16 + n) * 128 + q * 8;
        #pragma unroll
        for (int kk = 0; kk < 4; ++kk)
            aw[kk] = *(const bf16x8*)(wrow + kk * 32);
        float4 b4 = *(const float4*)&bias[c * 16 + q * 4];
        #pragma unroll
        for (int g = 0; g < 4; ++g) {
            f32x4 acc = {0.f, 0.f, 0.f, 0.f};
            #pragma unroll
            for (int kk = 0; kk < 4; ++kk)
                acc = __builtin_amdgcn_mfma_f32_16x16x32_bf16(aw[kk], bx[g][kk], acc, 0, 0, 0);
            if (node[g] < N_NODES) {
                float4 o;
                o.x = acc[0] + b4.x; o.y = acc[1] + b4.y;
                o.z = acc[2] + b4.z; o.w = acc[3] + b4.w;
                *(float4*)&out[(size_t)node[g] * 128 + c * 16 + q * 4] = o;
            }
        }
    }
}

// ---------------- phase 1 (MFMA): dst-grouped messages, permuted rows -------
// msg row layout: elem = q*32 + c*4 + r  <->  out col = c*16 + q*4 + r.
// Lane (n,q) owns a contiguous 64B span of its row: full-sector stores.
__global__ __launch_bounds__(256, 4) void k_msg_mfma(const u16* __restrict__ xb,
                                                     const u16* __restrict__ wt,
                                                     const int* __restrict__ src,
                                                     const int* __restrict__ etype,
                                                     const int* __restrict__ sorted,
                                                     const int* __restrict__ pos,
                                                     u16* __restrict__ msgs) {
    __shared__ int s_src[256], s_pos[256];
    __shared__ int s_relw[4];
    int t = threadIdx.x;
    int e0 = blockIdx.x * 256;
    int eid = sorted[e0 + t];
    if (eid < N_EDGES) {
        s_src[t] = src[eid];
        s_pos[t] = pos[e0 + t];
    } else {
        s_src[t] = 0;
        s_pos[t] = N_EDGES + t;              // dump rows (cross-block race OK)
    }
    if ((t & 63) == 0)
        s_relw[t >> 6] = (eid < N_EDGES) ? etype[eid] : (eid - N_EDGES);
    __syncthreads();

    int w = t >> 6, lane = t & 63;
    int n = lane & 15, q = lane >> 4;
    const u16* wr = wt + (size_t)s_relw[w] * 16384;
    int ebase = w * 64;

    #pragma unroll
    for (int g = 0; g < 4; ++g) {
        int en = ebase + g * 16 + n;
        const u16* xrow = xb + (size_t)s_src[en] * 128 + q * 8;
        int p = s_pos[en];
        bf16x8 bx[4];
        #pragma unroll
        for (int kk = 0; kk < 4; ++kk)
            bx[kk] = *(const bf16x8*)(xrow + kk * 32);
        uint4 uv[4];
        #pragma unroll
        for (int c = 0; c < 8; ++c) {
            bf16x8 aw[4];
            const u16* wrow = wr + (size_t)(c * 16 + n) * 128 + q * 8;
            #pragma unroll
            for (int kk = 0; kk < 4; ++kk)
                aw[kk] = *(const bf16x8*)(wrow + kk * 32);
            f32x4 acc = {0.f, 0.f, 0.f, 0.f};
            #pragma unroll
            for (int kk = 0; kk < 4; ++kk)
                acc = __builtin_amdgcn_mfma_f32_16x16x32_bf16(aw[kk], bx[kk], acc, 0, 0, 0);
            u32 lo = (u32)f2bf(acc[0]) | ((u32)f2bf(acc[1]) << 16);
            u32 hi = (u32)f2bf(acc[2]) | ((u32)f2bf(acc[3]) << 16);
            if ((c & 1) == 0) { uv[c >> 1].x = lo; uv[c >> 1].y = hi; }
            else             { uv[c >> 1].z = lo; uv[c >> 1].w = hi; }
        }
        u32* mrow = (u32*)(msgs + (size_t)p * 128 + q * 32);  // contiguous 64B
        #pragma unroll
        for (int j = 0; j < 4; ++j)
            *(uint4*)(mrow + j * 4) = uv[j];
    }
}

// ---------------- phase 2: per-node gather + relu (permuted decode) ---------
// wave per node, 2 rows/iter, uint2/lane (512B per wave-instr).
__global__ __launch_bounds__(256) void k_gather(const int* __restrict__ row_ptr,
                                                const u16* __restrict__ msgs,
                                                float* __restrict__ out) {
    int wid  = (blockIdx.x * 256 + threadIdx.x) >> 6;
    int lane = threadIdx.x & 63;
    if (wid >= N_NODES) return;
    int r0 = row_ptr[wid], r1 = row_ptr[wid + 1];
    int h = lane & 31, half = lane >> 5;
    const uint2* m = (const uint2*)msgs;     // 8B units; row stride 32
    float s0 = 0.f, s1 = 0.f, s2 = 0.f, s3 = 0.f;
    for (int i = r0 + half; i < r1; i += 2) {
        uint2 v = m[(size_t)i * 32 + h];     // elems 4h..4h+3 of row i
        s0 += bf2f((u16)(v.x & 0xffffu)); s1 += bf2f((u16)(v.x >> 16));
        s2 += bf2f((u16)(v.y & 0xffffu)); s3 += bf2f((u16)(v.y >> 16));
    }
    s0 += __shfl_xor(s0, 32); s1 += __shfl_xor(s1, 32);
    s2 += __shfl_xor(s2, 32); s3 += __shfl_xor(s3, 32);
    if (half == 0) {
        int col = 16 * (h & 7) + 4 * (h >> 3);   // perm elem 4h+i -> col+i
        float4* o = (float4*)(out + (size_t)wid * 128 + col);
        float4 v = *o;
        v.x = fmaxf(v.x + s0, 0.f); v.y = fmaxf(v.y + s1, 0.f);
        v.z = fmaxf(v.z + s2, 0.f); v.w = fmaxf(v.w + s3, 0.f);
        *o = v;
    }
}

// ---------------- fallback (atomic path, small ws) ----------------
__global__ __launch_bounds__(128) void k_self_old(const float* __restrict__ x,
                                                  const float* __restrict__ sw,
                                                  const float* __restrict__ bias,
                                                  float* __restrict__ out) {
    __shared__ float s_x[8][IN_DIM];
    int t = threadIdx.x;
    int n0 = blockIdx.x * 8;
    for (int i = t; i < 8 * IN_DIM; i += 128) {
        int r = i >> 7, j = i & 127;
        s_x[r][j] = x[(size_t)(n0 + r) * IN_DIM + j];
    }
    __syncthreads();
    float acc[8] = {0.f,0.f,0.f,0.f,0.f,0.f,0.f,0.f};
    for (int k = 0; k < IN_DIM; ++k) {
        float w = sw[k * OUT_DIM + t];
        #pragma unroll
        for (int i = 0; i < 8; ++i) acc[i] += s_x[i][k] * w;
    }
    float b = bias[t];
    #pragma unroll
    for (int i = 0; i < 8; ++i)
        out[(size_t)(n0 + i) * OUT_DIM + t] = acc[i] + b;
}

__global__ __launch_bounds__(256) void k_scatter_rel(const int* __restrict__ etype,
                                                     int* __restrict__ cursor,
                                                     int* __restrict__ sorted) {
    __shared__ int bins[N_REL];
    __shared__ int base[N_REL];
    int t = threadIdx.x;
    if (t < N_REL) bins[t] = 0;
    __syncthreads();
    int e = blockIdx.x * 256 + t;
    int rel = 0;
    bool valid = (e < N_EDGES);
    if (valid) { rel = etype[e]; atomicAdd(&bins[rel], 1); }
    __syncthreads();
    if (t < N_REL) {
        base[t] = bins[t] ? atomicAdd(&cursor[t], bins[t]) : 0;
        bins[t] = 0;
    }
    __syncthreads();
    if (valid) {
        int p = atomicAdd(&bins[rel], 1);
        sorted[base[rel] + p] = e;
    }
}

__global__ __launch_bounds__(256) void k_edge_atomic(const float* __restrict__ x,
                                              const float* __restrict__ rw,
                                              const int* __restrict__ src,
                                              const int* __restrict__ dst,
                                              const int* __restrict__ etype,
                                              const int* __restrict__ sorted,
                                              float* __restrict__ out) {
    __shared__ int s_src[EPB], s_dst[EPB], s_rel[EPB];
    __shared__ float s_x[EPB][IN_DIM];
    int t = threadIdx.x;
    int e0 = blockIdx.x * EPB;
    if (t < EPB) {
        int eid = sorted[e0 + t];
        s_src[t] = src[eid]; s_dst[t] = dst[eid]; s_rel[t] = etype[eid];
    }
    __syncthreads();
    for (int i = t; i < EPB * IN_DIM; i += 256) {
        int e = i >> 7, j = i & 127;
        s_x[e][j] = x[(size_t)s_src[e] * IN_DIM + j];
    }
    int rel0 = s_rel[0];
    bool uni = true;
    for (int i = 1; i < EPB; ++i) uni &= (s_rel[i] == rel0);
    __syncthreads();
    int cg = t & 31, eg = t >> 5;
    for (int i = 0; i < 8; ++i) {
        int e = eg * 8 + i;
        int rel = uni ? rel0 : s_rel[e];
        const float4* Wr = (const float4*)(rw + (size_t)rel * IN_DIM * OUT_DIM);
        float a0=0.f, a1=0.f, a2=0.f, a3=0.f;
        for (int k = 0; k < 128; ++k) {
            float4 w = Wr[k * 32 + cg];
            float xv = s_x[e][k];
            a0 += xv * w.x; a1 += xv * w.y; a2 += xv * w.z; a3 += xv * w.w;
        }
        float* o = out + (size_t)s_dst[e] * OUT_DIM + cg * 4;
        atomicAdd(o + 0, a0); atomicAdd(o + 1, a1);
        atomicAdd(o + 2, a2); atomicAdd(o + 3, a3);
    }
}

__global__ void k_relu(float* __restrict__ out) {
    int i = blockIdx.x * blockDim.x + threadIdx.x;
    float4* o4 = (float4*)out;
    const int n4 = N_NODES * OUT_DIM / 4;
    if (i < n4) {
        float4 v = o4[i];
        v.x = fmaxf(v.x, 0.f); v.y = fmaxf(v.y, 0.f);
        v.z = fmaxf(v.z, 0.f); v.w = fmaxf(v.w, 0.f);
        o4[i] = v;
    }
}

extern "C" void kernel_launch(void* const* d_in, const int* in_sizes, int n_in,
                              void* d_out, int out_size, void* d_ws, size_t ws_size,
                              hipStream_t stream) {
    const float* x     = (const float*)d_in[0];
    const int*   eidx  = (const int*)d_in[1];
    const int*   etype = (const int*)d_in[2];
    const float* rw    = (const float*)d_in[3];
    const float* sw    = (const float*)d_in[4];
    const float* bias  = (const float*)d_in[5];
    float* out = (float*)d_out;
    const int* src = eidx;
    const int* dst = eidx + N_EDGES;

    // ---- workspace layout ----
    int* counts_rel = (int*)d_ws;                  // 16
    int* cursor_rel = counts_rel + 16;             // 16
    int* seg        = cursor_rel + 16;             // 32 (17 used)
    int* part       = seg + 32;                    // 512
    int* dst_count  = part + 512;                  // N
    int* row_ptr    = dst_count + N_NODES;         // N+1
    int* cursor_dst = row_ptr + N_NODES + 1;       // N
    int* sorted     = cursor_dst + N_NODES;        // E+PAD
    int* pos        = sorted + N_EDGES + PAD;      // E+PAD
    size_t off = (((char*)(pos + N_EDGES + PAD) - (char*)d_ws) + 255) & ~(size_t)255;
    u16* xb   = (u16*)((char*)d_ws + off);         // N*128 bf16
    u16* wtb  = xb + (size_t)N_NODES * 128;        // 17*16384 bf16 (transposed)
    u16* msgs = wtb + 17 * 16384;                  // (E+PAD)*128 bf16, dst-grouped
    size_t need = (size_t)((char*)(msgs + (size_t)(N_EDGES + PAD) * 128) - (char*)d_ws);

    const int EB  = (N_EDGES + 255) / 256;         // 2500
    const int EBP = (N_EDGES + PAD) / 256;         // 2504

    if (ws_size >= need) {
        hipMemsetAsync(d_ws, 0, (size_t)(576 + N_NODES) * sizeof(int), stream);
        k_cvt<<<CVT_XB + CVT_WB, 256, 0, stream>>>(x, rw, sw, xb, wtb);
        k_hist<<<EB, 256, 0, stream>>>(etype, dst, counts_rel, dst_count);
        k_scan_rel_pad<<<1, 64, 0, stream>>>(counts_rel, cursor_rel, seg);
        k_scan1<<<NB_SCAN, 256, 0, stream>>>(dst_count, row_ptr, part);
        k_scan2<<<1, 512, 0, stream>>>(part);
        k_scan3<<<NB_SCAN, 256, 0, stream>>>(row_ptr, part, cursor_dst);
        k_fill<<<1, 256, 0, stream>>>(counts_rel, seg, sorted);
        k_scatter_pos<<<EB, 256, 0, stream>>>(etype, dst, cursor_rel, cursor_dst, sorted, pos);

        k_self_mfma<<<(N_NODES + 255) / 256, 256, 0, stream>>>(xb, wtb, bias, out);
        k_msg_mfma<<<EBP, 256, 0, stream>>>(xb, wtb, src, etype, sorted, pos, msgs);
        k_gather<<<(N_NODES * 64 + 255) / 256, 256, 0, stream>>>(row_ptr, msgs, out);
    } else {
        // fallback: atomic path (needs only rel-sort scratch)
        hipMemsetAsync(counts_rel, 0, 16 * sizeof(int), stream);
        k_hist_rel<<<EB, 256, 0, stream>>>(etype, counts_rel);
        k_scan_rel<<<1, 64, 0, stream>>>(counts_rel, cursor_rel);
        k_scatter_rel<<<EB, 256, 0, stream>>>(etype, cursor_rel, sorted);
        k_self_old<<<N_NODES / 8, 128, 0, stream>>>(x, sw, bias, out);
        k_edge_atomic<<<N_EDGES / EPB, 256, 0, stream>>>(x, rw, src, dst, etype, sorted, out);
        k_relu<<<(N_NODES * OUT_DIM / 4 + 255) / 256, 256, 0, stream>>>(out);
    }
}

// Round 6
// 465.716 us; speedup vs baseline: 1.0180x; 1.0180x over previous
//
#include <hip/hip_runtime.h>

#define N_NODES 100000
#define N_EDGES 640000
#define IN_DIM  128
#define OUT_DIM 128
#define N_REL   16
#define EPB     64
#define PAD     1024                     // relation-padding slop (16*63 rounded up)
#define NB_SCAN ((N_NODES + 255) / 256)
#define CVT_XB  (N_NODES * IN_DIM / 4 / 256)   // 12500 blocks for x
#define CVT_WB  (17 * 16384 / 256)             // 1088 blocks for W
#define HIST_B  ((N_EDGES + 255) / 256)        // 2500 hist blocks

typedef unsigned short u16;
typedef unsigned int   u32;
typedef __attribute__((ext_vector_type(8))) short bf16x8;
typedef __attribute__((ext_vector_type(4))) float f32x4;

__device__ inline u16 f2bf(float f) {               // round-to-nearest-even
    u32 u = __builtin_bit_cast(u32, f);
    return (u16)((u + 0x7fffu + ((u >> 16) & 1u)) >> 16);
}
__device__ inline float bf2f(u16 s) {
    u32 u = ((u32)s) << 16;
    return __builtin_bit_cast(float, u);
}

// ---------------- fused preprocessing pass 1: cvt-x, cvt-W, histograms ------
__global__ __launch_bounds__(256) void k_pre(const float* __restrict__ x,
                                             const float* __restrict__ rw,
                                             const float* __restrict__ sw,
                                             const int* __restrict__ etype,
                                             const int* __restrict__ dst,
                                             u16* __restrict__ xb,
                                             u16* __restrict__ wt,
                                             int* __restrict__ counts_rel,
                                             int* __restrict__ dst_count) {
    int b = blockIdx.x, t = threadIdx.x;
    if (b < CVT_XB) {
        int i = b * 256 + t;
        float4 v = ((const float4*)x)[i];
        ushort4 p; p.x = f2bf(v.x); p.y = f2bf(v.y); p.z = f2bf(v.z); p.w = f2bf(v.w);
        ((ushort4*)xb)[i] = p;
    } else if (b < CVT_XB + CVT_WB) {
        int i = (b - CVT_XB) * 256 + t;     // over 17*16384, exact
        int r = i >> 14, rem = i & 16383, n = rem & 127;
        float v = (r < 16) ? rw[i] : sw[rem];
        int k = rem >> 7;
        wt[(size_t)r * 16384 + n * 128 + k] = f2bf(v);
    } else {
        __shared__ int bins[N_REL];
        if (t < N_REL) bins[t] = 0;
        __syncthreads();
        int e = (b - CVT_XB - CVT_WB) * 256 + t;
        if (e < N_EDGES) {
            atomicAdd(&bins[etype[e]], 1);
            atomicAdd(&dst_count[dst[e]], 1);
        }
        __syncthreads();
        if (t < N_REL && bins[t]) atomicAdd(&counts_rel[t], bins[t]);
    }
}

// ---------------- fused: padded relation scan + sentinel fill (1 block) -----
__global__ __launch_bounds__(256) void k_mid(const int* __restrict__ counts,
                                             int* __restrict__ cursor,
                                             int* __restrict__ seg,
                                             int* __restrict__ sorted) {
    int t = threadIdx.x;
    if (t == 0) {
        int s = 0;
        for (int r = 0; r < N_REL; ++r) {
            cursor[r] = s; seg[r] = s;
            s += (counts[r] + 63) & ~63;
        }
        seg[N_REL] = s;
    }
    __syncthreads();
    for (int r = 0; r < N_REL; ++r) {
        int b = seg[r] + counts[r], e2 = seg[r + 1];
        if (b + t < e2) sorted[b + t] = N_EDGES + r;   // pad < 64 per segment
    }
    for (int i = seg[N_REL] + t; i < N_EDGES + PAD; i += 256)
        sorted[i] = N_EDGES + (N_REL - 1);
}

// ---------------- exclusive scan over dst_count -> row_ptr ----------------
__global__ __launch_bounds__(256) void k_scan1(const int* __restrict__ dst_count,
                                               int* __restrict__ row_ptr,
                                               int* __restrict__ part) {
    __shared__ int buf[2][256];
    int t = threadIdx.x;
    int i = blockIdx.x * 256 + t;
    int v = (i < N_NODES) ? dst_count[i] : 0;
    buf[0][t] = v;
    __syncthreads();
    int cur = 0;
    #pragma unroll
    for (int off = 1; off < 256; off <<= 1) {
        int nxt = cur ^ 1;
        int s = buf[cur][t];
        if (t >= off) s += buf[cur][t - off];
        buf[nxt][t] = s;
        __syncthreads();
        cur = nxt;
    }
    int inc = buf[cur][t];
    if (i < N_NODES) row_ptr[i] = inc - v;
    if (t == 255) part[blockIdx.x] = inc;
}

__global__ __launch_bounds__(512) void k_scan2(int* __restrict__ part) {
    __shared__ int buf[2][512];
    int t = threadIdx.x;
    int v = (t < NB_SCAN) ? part[t] : 0;
    buf[0][t] = v;
    __syncthreads();
    int cur = 0;
    #pragma unroll
    for (int off = 1; off < 512; off <<= 1) {
        int nxt = cur ^ 1;
        int s = buf[cur][t];
        if (t >= off) s += buf[cur][t - off];
        buf[nxt][t] = s;
        __syncthreads();
        cur = nxt;
    }
    int inc = buf[cur][t];
    if (t < NB_SCAN) part[t] = inc - v;
}

__global__ __launch_bounds__(256) void k_scan3(int* __restrict__ row_ptr,
                                               const int* __restrict__ part,
                                               int* __restrict__ cursor_dst) {
    int t = threadIdx.x;
    int i = blockIdx.x * 256 + t;
    if (i < N_NODES) {
        int r = row_ptr[i] + part[blockIdx.x];
        row_ptr[i] = r;
        cursor_dst[i] = r;
    }
    if (i == 0) row_ptr[N_NODES] = N_EDGES;
}

// relation counting-sort + dst-grouped position, fused
__global__ __launch_bounds__(256) void k_scatter_pos(const int* __restrict__ etype,
                                                     const int* __restrict__ dst,
                                                     int* __restrict__ cursor_rel,
                                                     int* __restrict__ cursor_dst,
                                                     int* __restrict__ sorted,
                                                     int* __restrict__ pos) {
    __shared__ int bins[N_REL];
    __shared__ int base[N_REL];
    int t = threadIdx.x;
    if (t < N_REL) bins[t] = 0;
    __syncthreads();
    int e = blockIdx.x * 256 + t;
    int rel = 0;
    bool valid = (e < N_EDGES);
    if (valid) { rel = etype[e]; atomicAdd(&bins[rel], 1); }
    __syncthreads();
    if (t < N_REL) {
        base[t] = bins[t] ? atomicAdd(&cursor_rel[t], bins[t]) : 0;
        bins[t] = 0;
    }
    __syncthreads();
    if (valid) {
        int slot = base[rel] + atomicAdd(&bins[rel], 1);
        sorted[slot] = e;
        pos[slot] = atomicAdd(&cursor_dst[dst[e]], 1);
    }
}

// ---------------- self transform (MFMA, LDS-free) ----------------
__global__ __launch_bounds__(256, 4) void k_self_mfma(const u16* __restrict__ xb,
                                                      const u16* __restrict__ wt,
                                                      const float* __restrict__ bias,
                                                      float* __restrict__ out) {
    int t = threadIdx.x;
    int w = t >> 6, lane = t & 63;
    int n = lane & 15, q = lane >> 4;
    int n0 = blockIdx.x * 256 + w * 64;
    const u16* wr = wt + (size_t)16 * 16384;     // self weight = "relation 16"

    bf16x8 bx[4][4];
    int node[4];
    #pragma unroll
    for (int g = 0; g < 4; ++g) {
        node[g] = n0 + g * 16 + n;
        int rn = node[g] < N_NODES ? node[g] : N_NODES - 1;
        const u16* xrow = xb + (size_t)rn * 128 + q * 8;
        #pragma unroll
        for (int kk = 0; kk < 4; ++kk)
            bx[g][kk] = *(const bf16x8*)(xrow + kk * 32);
    }
    #pragma unroll
    for (int c = 0; c < 8; ++c) {
        bf16x8 aw[4];
        const u16* wrow = wr + (c * 16 + n) * 128 + q * 8;
        #pragma unroll
        for (int kk = 0; kk < 4; ++kk)
            aw[kk] = *(const bf16x8*)(wrow + kk * 32);
        float4 b4 = *(const float4*)&bias[c * 16 + q * 4];
        #pragma unroll
        for (int g = 0; g < 4; ++g) {
            f32x4 acc = {0.f, 0.f, 0.f, 0.f};
            #pragma unroll
            for (int kk = 0; kk < 4; ++kk)
                acc = __builtin_amdgcn_mfma_f32_16x16x32_bf16(aw[kk], bx[g][kk], acc, 0, 0, 0);
            if (node[g] < N_NODES) {
                float4 o;
                o.x = acc[0] + b4.x; o.y = acc[1] + b4.y;
                o.z = acc[2] + b4.z; o.w = acc[3] + b4.w;
                *(float4*)&out[(size_t)node[g] * 128 + c * 16 + q * 4] = o;
            }
        }
    }
}

// ---------------- phase 1 (MFMA): 16 edges per wave, no LDS, no barriers ----
// msg row layout: elem = q*32 + c*4 + r  <->  out col = c*16 + q*4 + r.
__global__ __launch_bounds__(256, 4) void k_msg_mfma(const u16* __restrict__ xb,
                                                     const u16* __restrict__ wt,
                                                     const int* __restrict__ src,
                                                     const int* __restrict__ etype,
                                                     const int* __restrict__ sorted,
                                                     const int* __restrict__ pos,
                                                     u16* __restrict__ msgs) {
    int t = threadIdx.x;
    int wv = t >> 6, lane = t & 63;
    int e0 = blockIdx.x * 64 + wv * 16;          // 16 rel-uniform edges per wave

    int sv = 0, pv = 0, rv = 0;
    if (lane < 16) {
        int eid = sorted[e0 + lane];
        if (eid < N_EDGES) {
            sv = src[eid];
            pv = pos[e0 + lane];
            rv = etype[eid];
        } else {
            sv = 0;
            pv = N_EDGES + ((e0 + lane) & (PAD - 1));   // dump row; races OK
            rv = eid - N_EDGES;                          // sentinel encodes rel
        }
    }
    int n = lane & 15, q = lane >> 4;
    int my_src = __shfl(sv, n);
    int my_pos = __shfl(pv, n);
    int rel    = __shfl(rv, 0);

    const u16* wr = wt + (size_t)rel * 16384;
    bf16x8 bx[4];
    const u16* xrow = xb + (size_t)my_src * 128 + q * 8;
    #pragma unroll
    for (int kk = 0; kk < 4; ++kk)
        bx[kk] = *(const bf16x8*)(xrow + kk * 32);

    uint4 uv[4];
    #pragma unroll
    for (int c = 0; c < 8; ++c) {
        bf16x8 aw[4];
        const u16* wrow = wr + (size_t)(c * 16 + n) * 128 + q * 8;
        #pragma unroll
        for (int kk = 0; kk < 4; ++kk)
            aw[kk] = *(const bf16x8*)(wrow + kk * 32);
        f32x4 acc = {0.f, 0.f, 0.f, 0.f};
        #pragma unroll
        for (int kk = 0; kk < 4; ++kk)
            acc = __builtin_amdgcn_mfma_f32_16x16x32_bf16(aw[kk], bx[kk], acc, 0, 0, 0);
        u32 lo = (u32)f2bf(acc[0]) | ((u32)f2bf(acc[1]) << 16);
        u32 hi = (u32)f2bf(acc[2]) | ((u32)f2bf(acc[3]) << 16);
        if ((c & 1) == 0) { uv[c >> 1].x = lo; uv[c >> 1].y = hi; }
        else              { uv[c >> 1].z = lo; uv[c >> 1].w = hi; }
    }
    u32* mrow = (u32*)(msgs + (size_t)my_pos * 128 + q * 32);   // contiguous 64B
    #pragma unroll
    for (int j = 0; j < 4; ++j)
        *(uint4*)(mrow + j * 4) = uv[j];
}

// ---------------- phase 2: per-node gather + relu (uint4/lane) --------------
// wave per node; quarter-wave (16 lanes x 16B) covers one 256B row; 4 rows/iter.
__global__ __launch_bounds__(256) void k_gather(const int* __restrict__ row_ptr,
                                                const u16* __restrict__ msgs,
                                                float* __restrict__ out) {
    int wid  = (blockIdx.x * 256 + threadIdx.x) >> 6;
    int lane = threadIdx.x & 63;
    if (wid >= N_NODES) return;
    int r0 = row_ptr[wid], r1 = row_ptr[wid + 1];
    int h = lane & 15, quarter = lane >> 4;
    const uint4* m = (const uint4*)msgs;          // 16B units; row = 16 units
    float s[8] = {0.f,0.f,0.f,0.f,0.f,0.f,0.f,0.f};
    for (int i = r0 + quarter; i < r1; i += 4) {
        uint4 v = m[(size_t)i * 16 + h];
        s[0] += bf2f((u16)(v.x & 0xffffu)); s[1] += bf2f((u16)(v.x >> 16));
        s[2] += bf2f((u16)(v.y & 0xffffu)); s[3] += bf2f((u16)(v.y >> 16));
        s[4] += bf2f((u16)(v.z & 0xffffu)); s[5] += bf2f((u16)(v.z >> 16));
        s[6] += bf2f((u16)(v.w & 0xffffu)); s[7] += bf2f((u16)(v.w >> 16));
    }
    #pragma unroll
    for (int j = 0; j < 8; ++j) {
        s[j] += __shfl_xor(s[j], 16);
        s[j] += __shfl_xor(s[j], 32);
    }
    if (quarter == 0) {
        // elems 8h..8h+7 -> cols: c0=(2h)&7, c1=(2h+1)&7, qq=h>>2
        int c0 = (2 * h) & 7, c1 = (2 * h + 1) & 7, qq = h >> 2;
        float* ob = out + (size_t)wid * 128;
        float4* o0 = (float4*)(ob + c0 * 16 + qq * 4);
        float4* o1 = (float4*)(ob + c1 * 16 + qq * 4);
        float4 v0 = *o0, v1 = *o1;
        v0.x = fmaxf(v0.x + s[0], 0.f); v0.y = fmaxf(v0.y + s[1], 0.f);
        v0.z = fmaxf(v0.z + s[2], 0.f); v0.w = fmaxf(v0.w + s[3], 0.f);
        v1.x = fmaxf(v1.x + s[4], 0.f); v1.y = fmaxf(v1.y + s[5], 0.f);
        v1.z = fmaxf(v1.z + s[6], 0.f); v1.w = fmaxf(v1.w + s[7], 0.f);
        *o0 = v0; *o1 = v1;
    }
}

// ---------------- fallback (atomic path, small ws) ----------------
__global__ __launch_bounds__(128) void k_self_old(const float* __restrict__ x,
                                                  const float* __restrict__ sw,
                                                  const float* __restrict__ bias,
                                                  float* __restrict__ out) {
    __shared__ float s_x[8][IN_DIM];
    int t = threadIdx.x;
    int n0 = blockIdx.x * 8;
    for (int i = t; i < 8 * IN_DIM; i += 128) {
        int r = i >> 7, j = i & 127;
        s_x[r][j] = x[(size_t)(n0 + r) * IN_DIM + j];
    }
    __syncthreads();
    float acc[8] = {0.f,0.f,0.f,0.f,0.f,0.f,0.f,0.f};
    for (int k = 0; k < IN_DIM; ++k) {
        float w = sw[k * OUT_DIM + t];
        #pragma unroll
        for (int i = 0; i < 8; ++i) acc[i] += s_x[i][k] * w;
    }
    float b = bias[t];
    #pragma unroll
    for (int i = 0; i < 8; ++i)
        out[(size_t)(n0 + i) * OUT_DIM + t] = acc[i] + b;
}

__global__ __launch_bounds__(256) void k_hist_rel(const int* __restrict__ etype,
                                                  int* __restrict__ counts_rel) {
    __shared__ int bins[N_REL];
    int t = threadIdx.x;
    if (t < N_REL) bins[t] = 0;
    __syncthreads();
    int e = blockIdx.x * 256 + t;
    if (e < N_EDGES) atomicAdd(&bins[etype[e]], 1);
    __syncthreads();
    if (t < N_REL && bins[t]) atomicAdd(&counts_rel[t], bins[t]);
}

__global__ void k_scan_rel(const int* __restrict__ counts, int* __restrict__ cursor) {
    if (threadIdx.x == 0) {
        int s = 0;
        for (int r = 0; r < N_REL; ++r) { cursor[r] = s; s += counts[r]; }
    }
}

__global__ __launch_bounds__(256) void k_scatter_rel(const int* __restrict__ etype,
                                                     int* __restrict__ cursor,
                                                     int* __restrict__ sorted) {
    __shared__ int bins[N_REL];
    __shared__ int base[N_REL];
    int t = threadIdx.x;
    if (t < N_REL) bins[t] = 0;
    __syncthreads();
    int e = blockIdx.x * 256 + t;
    int rel = 0;
    bool valid = (e < N_EDGES);
    if (valid) { rel = etype[e]; atomicAdd(&bins[rel], 1); }
    __syncthreads();
    if (t < N_REL) {
        base[t] = bins[t] ? atomicAdd(&cursor[t], bins[t]) : 0;
        bins[t] = 0;
    }
    __syncthreads();
    if (valid) {
        int p = atomicAdd(&bins[rel], 1);
        sorted[base[rel] + p] = e;
    }
}

__global__ __launch_bounds__(256) void k_edge_atomic(const float* __restrict__ x,
                                              const float* __restrict__ rw,
                                              const int* __restrict__ src,
                                              const int* __restrict__ dst,
                                              const int* __restrict__ etype,
                                              const int* __restrict__ sorted,
                                              float* __restrict__ out) {
    __shared__ int s_src[EPB], s_dst[EPB], s_rel[EPB];
    __shared__ float s_x[EPB][IN_DIM];
    int t = threadIdx.x;
    int e0 = blockIdx.x * EPB;
    if (t < EPB) {
        int eid = sorted[e0 + t];
        s_src[t] = src[eid]; s_dst[t] = dst[eid]; s_rel[t] = etype[eid];
    }
    __syncthreads();
    for (int i = t; i < EPB * IN_DIM; i += 256) {
        int e = i >> 7, j = i & 127;
        s_x[e][j] = x[(size_t)s_src[e] * IN_DIM + j];
    }
    int rel0 = s_rel[0];
    bool uni = true;
    for (int i = 1; i < EPB; ++i) uni &= (s_rel[i] == rel0);
    __syncthreads();
    int cg = t & 31, eg = t >> 5;
    for (int i = 0; i < 8; ++i) {
        int e = eg * 8 + i;
        int rel = uni ? rel0 : s_rel[e];
        const float4* Wr = (const float4*)(rw + (size_t)rel * IN_DIM * OUT_DIM);
        float a0=0.f, a1=0.f, a2=0.f, a3=0.f;
        for (int k = 0; k < 128; ++k) {
            float4 w = Wr[k * 32 + cg];
            float xv = s_x[e][k];
            a0 += xv * w.x; a1 += xv * w.y; a2 += xv * w.z; a3 += xv * w.w;
        }
        float* o = out + (size_t)s_dst[e] * OUT_DIM + cg * 4;
        atomicAdd(o + 0, a0); atomicAdd(o + 1, a1);
        atomicAdd(o + 2, a2); atomicAdd(o + 3, a3);
    }
}

__global__ void k_relu(float* __restrict__ out) {
    int i = blockIdx.x * blockDim.x + threadIdx.x;
    float4* o4 = (float4*)out;
    const int n4 = N_NODES * OUT_DIM / 4;
    if (i < n4) {
        float4 v = o4[i];
        v.x = fmaxf(v.x, 0.f); v.y = fmaxf(v.y, 0.f);
        v.z = fmaxf(v.z, 0.f); v.w = fmaxf(v.w, 0.f);
        o4[i] = v;
    }
}

extern "C" void kernel_launch(void* const* d_in, const int* in_sizes, int n_in,
                              void* d_out, int out_size, void* d_ws, size_t ws_size,
                              hipStream_t stream) {
    const float* x     = (const float*)d_in[0];
    const int*   eidx  = (const int*)d_in[1];
    const int*   etype = (const int*)d_in[2];
    const float* rw    = (const float*)d_in[3];
    const float* sw    = (const float*)d_in[4];
    const float* bias  = (const float*)d_in[5];
    float* out = (float*)d_out;
    const int* src = eidx;
    const int* dst = eidx + N_EDGES;

    // ---- workspace layout ----
    int* counts_rel = (int*)d_ws;                  // 16
    int* cursor_rel = counts_rel + 16;             // 16
    int* seg        = cursor_rel + 16;             // 32 (17 used)
    int* part       = seg + 32;                    // 512
    int* dst_count  = part + 512;                  // N
    int* row_ptr    = dst_count + N_NODES;         // N+1
    int* cursor_dst = row_ptr + N_NODES + 1;       // N
    int* sorted     = cursor_dst + N_NODES;        // E+PAD
    int* pos        = sorted + N_EDGES + PAD;      // E+PAD
    size_t off = (((char*)(pos + N_EDGES + PAD) - (char*)d_ws) + 255) & ~(size_t)255;
    u16* xb   = (u16*)((char*)d_ws + off);         // N*128 bf16
    u16* wtb  = xb + (size_t)N_NODES * 128;        // 17*16384 bf16 (transposed)
    u16* msgs = wtb + 17 * 16384;                  // (E+PAD)*128 bf16, dst-grouped
    size_t need = (size_t)((char*)(msgs + (size_t)(N_EDGES + PAD) * 128) - (char*)d_ws);

    const int EB = HIST_B;                         // 2500
    const int MB = (N_EDGES + PAD) / 64;           // 10016 blocks, 64 edges each

    if (ws_size >= need) {
        hipMemsetAsync(d_ws, 0, (size_t)(576 + N_NODES) * sizeof(int), stream);
        k_pre<<<CVT_XB + CVT_WB + EB, 256, 0, stream>>>(x, rw, sw, etype, dst,
                                                        xb, wtb, counts_rel, dst_count);
        k_mid<<<1, 256, 0, stream>>>(counts_rel, cursor_rel, seg, sorted);
        k_scan1<<<NB_SCAN, 256, 0, stream>>>(dst_count, row_ptr, part);
        k_scan2<<<1, 512, 0, stream>>>(part);
        k_scan3<<<NB_SCAN, 256, 0, stream>>>(row_ptr, part, cursor_dst);
        k_scatter_pos<<<EB, 256, 0, stream>>>(etype, dst, cursor_rel, cursor_dst, sorted, pos);

        k_self_mfma<<<(N_NODES + 255) / 256, 256, 0, stream>>>(xb, wtb, bias, out);
        k_msg_mfma<<<MB, 256, 0, stream>>>(xb, wtb, src, etype, sorted, pos, msgs);
        k_gather<<<(N_NODES * 64 + 255) / 256, 256, 0, stream>>>(row_ptr, msgs, out);
    } else {
        // fallback: atomic path (needs only rel-sort scratch)
        hipMemsetAsync(counts_rel, 0, 16 * sizeof(int), stream);
        k_hist_rel<<<EB, 256, 0, stream>>>(etype, counts_rel);
        k_scan_rel<<<1, 64, 0, stream>>>(counts_rel, cursor_rel);
        k_scatter_rel<<<EB, 256, 0, stream>>>(etype, cursor_rel, sorted);
        k_self_old<<<N_NODES / 8, 128, 0, stream>>>(x, sw, bias, out);
        k_edge_atomic<<<N_EDGES / EPB, 256, 0, stream>>>(x, rw, src, dst, etype, sorted, out);
        k_relu<<<(N_NODES * OUT_DIM / 4 + 255) / 256, 256, 0, stream>>>(out);
    }
}

// Round 7
// 369.198 us; speedup vs baseline: 1.2841x; 1.2614x over previous
//
#include <hip/hip_runtime.h>

#define N_NODES 100000
#define N_EDGES 640000
#define IN_DIM  128
#define OUT_DIM 128
#define N_REL   16
#define EPB     64
#define MEPB    128                      // edges per block in k_msg
#define PAD     2048                     // relation-padding slop (16*127 rounded up)
#define NB_SCAN ((N_NODES + 255) / 256)
#define CVT_XB  (N_NODES * IN_DIM / 4 / 256)   // 12500 blocks for x
#define CVT_WB  (17 * 16384 / 256)             // 1088 blocks for W
#define HIST_B  ((N_EDGES + 255) / 256)        // 2500 hist blocks

typedef unsigned short u16;
typedef unsigned int   u32;
typedef __attribute__((ext_vector_type(8))) short bf16x8;
typedef __attribute__((ext_vector_type(4))) float f32x4;

__device__ inline u16 f2bf(float f) {               // round-to-nearest-even
    u32 u = __builtin_bit_cast(u32, f);
    return (u16)((u + 0x7fffu + ((u >> 16) & 1u)) >> 16);
}
__device__ inline float bf2f(u16 s) {
    u32 u = ((u32)s) << 16;
    return __builtin_bit_cast(float, u);
}

// ---------------- fused preprocessing pass 1: cvt-x, cvt-W, histograms ------
__global__ __launch_bounds__(256) void k_pre(const float* __restrict__ x,
                                             const float* __restrict__ rw,
                                             const float* __restrict__ sw,
                                             const int* __restrict__ etype,
                                             const int* __restrict__ dst,
                                             u16* __restrict__ xb,
                                             u16* __restrict__ wt,
                                             int* __restrict__ counts_rel,
                                             int* __restrict__ dst_count) {
    int b = blockIdx.x, t = threadIdx.x;
    if (b < CVT_XB) {
        int i = b * 256 + t;
        float4 v = ((const float4*)x)[i];
        ushort4 p; p.x = f2bf(v.x); p.y = f2bf(v.y); p.z = f2bf(v.z); p.w = f2bf(v.w);
        ((ushort4*)xb)[i] = p;
    } else if (b < CVT_XB + CVT_WB) {
        int i = (b - CVT_XB) * 256 + t;     // over 17*16384, exact
        int r = i >> 14, rem = i & 16383, n = rem & 127;
        float v = (r < 16) ? rw[i] : sw[rem];
        int k = rem >> 7;
        wt[(size_t)r * 16384 + n * 128 + k] = f2bf(v);
    } else {
        __shared__ int bins[N_REL];
        if (t < N_REL) bins[t] = 0;
        __syncthreads();
        int e = (b - CVT_XB - CVT_WB) * 256 + t;
        if (e < N_EDGES) {
            atomicAdd(&bins[etype[e]], 1);
            atomicAdd(&dst_count[dst[e]], 1);
        }
        __syncthreads();
        if (t < N_REL && bins[t]) atomicAdd(&counts_rel[t], bins[t]);
    }
}

// ---------------- exclusive scan over dst_count -> row_ptr ----------------
__global__ __launch_bounds__(256) void k_scan1(const int* __restrict__ dst_count,
                                               int* __restrict__ row_ptr,
                                               int* __restrict__ part) {
    __shared__ int buf[2][256];
    int t = threadIdx.x;
    int i = blockIdx.x * 256 + t;
    int v = (i < N_NODES) ? dst_count[i] : 0;
    buf[0][t] = v;
    __syncthreads();
    int cur = 0;
    #pragma unroll
    for (int off = 1; off < 256; off <<= 1) {
        int nxt = cur ^ 1;
        int s = buf[cur][t];
        if (t >= off) s += buf[cur][t - off];
        buf[nxt][t] = s;
        __syncthreads();
        cur = nxt;
    }
    int inc = buf[cur][t];
    if (i < N_NODES) row_ptr[i] = inc - v;
    if (t == 255) part[blockIdx.x] = inc;
}

// fused: block 0 = scan of part[]; block 1 = padded rel-scan + sentinel fill
__global__ __launch_bounds__(512) void k_mid2(int* __restrict__ part,
                                              const int* __restrict__ counts,
                                              int* __restrict__ cursor,
                                              int* __restrict__ seg,
                                              int* __restrict__ sorted) {
    int t = threadIdx.x;
    if (blockIdx.x == 0) {
        __shared__ int buf[2][512];
        int v = (t < NB_SCAN) ? part[t] : 0;
        buf[0][t] = v;
        __syncthreads();
        int cur = 0;
        #pragma unroll
        for (int off = 1; off < 512; off <<= 1) {
            int nxt = cur ^ 1;
            int s = buf[cur][t];
            if (t >= off) s += buf[cur][t - off];
            buf[nxt][t] = s;
            __syncthreads();
            cur = nxt;
        }
        int inc = buf[cur][t];
        if (t < NB_SCAN) part[t] = inc - v;
    } else {
        __shared__ int s_seg[N_REL + 1];
        if (t == 0) {
            int s = 0;
            for (int r = 0; r < N_REL; ++r) {
                cursor[r] = s; seg[r] = s; s_seg[r] = s;
                s += (counts[r] + 127) & ~127;       // 128-align: k_msg blocks rel-uniform
            }
            seg[N_REL] = s; s_seg[N_REL] = s;
        }
        __syncthreads();
        for (int r = 0; r < N_REL; ++r) {
            int b = s_seg[r] + counts[r], e2 = s_seg[r + 1];
            if (b + t < e2) sorted[b + t] = N_EDGES + r;   // pad < 128 per segment
        }
        for (int i = s_seg[N_REL] + t; i < N_EDGES + PAD; i += 512)
            sorted[i] = N_EDGES + (N_REL - 1);
    }
}

__global__ __launch_bounds__(256) void k_scan3(int* __restrict__ row_ptr,
                                               const int* __restrict__ part,
                                               int* __restrict__ cursor_dst) {
    int t = threadIdx.x;
    int i = blockIdx.x * 256 + t;
    if (i < N_NODES) {
        int r = row_ptr[i] + part[blockIdx.x];
        row_ptr[i] = r;
        cursor_dst[i] = r;
    }
    if (i == 0) row_ptr[N_NODES] = N_EDGES;
}

// relation counting-sort + dst-grouped position, fused
__global__ __launch_bounds__(256) void k_scatter_pos(const int* __restrict__ etype,
                                                     const int* __restrict__ dst,
                                                     int* __restrict__ cursor_rel,
                                                     int* __restrict__ cursor_dst,
                                                     int* __restrict__ sorted,
                                                     int* __restrict__ pos) {
    __shared__ int bins[N_REL];
    __shared__ int base[N_REL];
    int t = threadIdx.x;
    if (t < N_REL) bins[t] = 0;
    __syncthreads();
    int e = blockIdx.x * 256 + t;
    int rel = 0;
    bool valid = (e < N_EDGES);
    if (valid) { rel = etype[e]; atomicAdd(&bins[rel], 1); }
    __syncthreads();
    if (t < N_REL) {
        base[t] = bins[t] ? atomicAdd(&cursor_rel[t], bins[t]) : 0;
        bins[t] = 0;
    }
    __syncthreads();
    if (valid) {
        int slot = base[rel] + atomicAdd(&bins[rel], 1);
        sorted[slot] = e;
        pos[slot] = atomicAdd(&cursor_dst[dst[e]], 1);
    }
}

// ---------------- self transform (MFMA, LDS-free) ----------------
__global__ __launch_bounds__(256, 4) void k_self_mfma(const u16* __restrict__ xb,
                                                      const u16* __restrict__ wt,
                                                      const float* __restrict__ bias,
                                                      float* __restrict__ out) {
    int t = threadIdx.x;
    int w = t >> 6, lane = t & 63;
    int n = lane & 15, q = lane >> 4;
    int n0 = blockIdx.x * 256 + w * 64;
    const u16* wr = wt + (size_t)16 * 16384;     // self weight = "relation 16"

    bf16x8 bx[4][4];
    int node[4];
    #pragma unroll
    for (int g = 0; g < 4; ++g) {
        node[g] = n0 + g * 16 + n;
        int rn = node[g] < N_NODES ? node[g] : N_NODES - 1;
        const u16* xrow = xb + (size_t)rn * 128 + q * 8;
        #pragma unroll
        for (int kk = 0; kk < 4; ++kk)
            bx[g][kk] = *(const bf16x8*)(xrow + kk * 32);
    }
    #pragma unroll
    for (int c = 0; c < 8; ++c) {
        bf16x8 aw[4];
        const u16* wrow = wr + (c * 16 + n) * 128 + q * 8;
        #pragma unroll
        for (int kk = 0; kk < 4; ++kk)
            aw[kk] = *(const bf16x8*)(wrow + kk * 32);
        float4 b4 = *(const float4*)&bias[c * 16 + q * 4];
        #pragma unroll
        for (int g = 0; g < 4; ++g) {
            f32x4 acc = {0.f, 0.f, 0.f, 0.f};
            #pragma unroll
            for (int kk = 0; kk < 4; ++kk)
                acc = __builtin_amdgcn_mfma_f32_16x16x32_bf16(aw[kk], bx[g][kk], acc, 0, 0, 0);
            if (node[g] < N_NODES) {
                float4 o;
                o.x = acc[0] + b4.x; o.y = acc[1] + b4.y;
                o.z = acc[2] + b4.z; o.w = acc[3] + b4.w;
                *(float4*)&out[(size_t)node[g] * 128 + c * 16 + q * 4] = o;
            }
        }
    }
}

// ---------------- phase 1 (MFMA): W in LDS, 128 edges/block, 32/wave --------
// msg row layout: elem = q*32 + c*4 + r  <->  out col = c*16 + q*4 + r.
// LDS W tile padded to 136 u16/row (272B): ds_read_b128 at the bank floor.
__global__ __launch_bounds__(256, 4) void k_msg_mfma(const u16* __restrict__ xb,
                                                     const u16* __restrict__ wt,
                                                     const int* __restrict__ src,
                                                     const int* __restrict__ etype,
                                                     const int* __restrict__ sorted,
                                                     const int* __restrict__ pos,
                                                     u16* __restrict__ msgs) {
    __shared__ u16 s_w[128 * 136];               // 34.8 KB
    __shared__ int s_src[MEPB], s_pos[MEPB];
    int t = threadIdx.x;
    int e0 = blockIdx.x * MEPB;

    // block-uniform relation (segments 128-aligned): broadcast load
    int ee = sorted[e0];
    int relb = (ee < N_EDGES) ? etype[ee] : (ee - N_EDGES);
    const uint4* wsrc = (const uint4*)(wt + (size_t)relb * 16384);
    for (int i = t; i < 2048; i += 256) {        // 32KB stage, coalesced
        uint4 v = wsrc[i];
        *(uint4*)&s_w[(i >> 4) * 136 + (i & 15) * 8] = v;
    }
    if (t < MEPB) {
        int eid = sorted[e0 + t];
        if (eid < N_EDGES) {
            s_src[t] = src[eid];
            s_pos[t] = pos[e0 + t];
        } else {
            s_src[t] = 0;
            s_pos[t] = N_EDGES + ((e0 + t) & (PAD - 1));   // dump rows; races OK
        }
    }
    __syncthreads();

    int wv = t >> 6, lane = t & 63;
    int n = lane & 15, q = lane >> 4;
    int eb = wv * 32;

    bf16x8 bx[2][4];
    int p[2];
    #pragma unroll
    for (int g = 0; g < 2; ++g) {
        int en = eb + g * 16 + n;
        const u16* xrow = xb + (size_t)s_src[en] * 128 + q * 8;
        p[g] = s_pos[en];
        #pragma unroll
        for (int kk = 0; kk < 4; ++kk)
            bx[g][kk] = *(const bf16x8*)(xrow + kk * 32);
    }

    uint4 uv[2][4];
    #pragma unroll
    for (int c = 0; c < 8; ++c) {
        bf16x8 aw[4];
        const u16* wrow = &s_w[(c * 16 + n) * 136 + q * 8];
        #pragma unroll
        for (int kk = 0; kk < 4; ++kk)
            aw[kk] = *(const bf16x8*)(wrow + kk * 32);
        #pragma unroll
        for (int g = 0; g < 2; ++g) {
            f32x4 acc = {0.f, 0.f, 0.f, 0.f};
            #pragma unroll
            for (int kk = 0; kk < 4; ++kk)
                acc = __builtin_amdgcn_mfma_f32_16x16x32_bf16(aw[kk], bx[g][kk], acc, 0, 0, 0);
            u32 lo = (u32)f2bf(acc[0]) | ((u32)f2bf(acc[1]) << 16);
            u32 hi = (u32)f2bf(acc[2]) | ((u32)f2bf(acc[3]) << 16);
            if ((c & 1) == 0) { uv[g][c >> 1].x = lo; uv[g][c >> 1].y = hi; }
            else              { uv[g][c >> 1].z = lo; uv[g][c >> 1].w = hi; }
        }
    }
    #pragma unroll
    for (int g = 0; g < 2; ++g) {
        u32* mrow = (u32*)(msgs + (size_t)p[g] * 128 + q * 32);  // contiguous 64B
        #pragma unroll
        for (int j = 0; j < 4; ++j)
            *(uint4*)(mrow + j * 4) = uv[g][j];
    }
}

// ---------------- phase 2: per-node gather + relu (uint4/lane) --------------
__global__ __launch_bounds__(256) void k_gather(const int* __restrict__ row_ptr,
                                                const u16* __restrict__ msgs,
                                                float* __restrict__ out) {
    int wid  = (blockIdx.x * 256 + threadIdx.x) >> 6;
    int lane = threadIdx.x & 63;
    if (wid >= N_NODES) return;
    int r0 = row_ptr[wid], r1 = row_ptr[wid + 1];
    int h = lane & 15, quarter = lane >> 4;
    const uint4* m = (const uint4*)msgs;          // 16B units; row = 16 units
    float s[8] = {0.f,0.f,0.f,0.f,0.f,0.f,0.f,0.f};
    for (int i = r0 + quarter; i < r1; i += 4) {
        uint4 v = m[(size_t)i * 16 + h];
        s[0] += bf2f((u16)(v.x & 0xffffu)); s[1] += bf2f((u16)(v.x >> 16));
        s[2] += bf2f((u16)(v.y & 0xffffu)); s[3] += bf2f((u16)(v.y >> 16));
        s[4] += bf2f((u16)(v.z & 0xffffu)); s[5] += bf2f((u16)(v.z >> 16));
        s[6] += bf2f((u16)(v.w & 0xffffu)); s[7] += bf2f((u16)(v.w >> 16));
    }
    #pragma unroll
    for (int j = 0; j < 8; ++j) {
        s[j] += __shfl_xor(s[j], 16);
        s[j] += __shfl_xor(s[j], 32);
    }
    if (quarter == 0) {
        int c0 = (2 * h) & 7, c1 = (2 * h + 1) & 7, qq = h >> 2;
        float* ob = out + (size_t)wid * 128;
        float4* o0 = (float4*)(ob + c0 * 16 + qq * 4);
        float4* o1 = (float4*)(ob + c1 * 16 + qq * 4);
        float4 v0 = *o0, v1 = *o1;
        v0.x = fmaxf(v0.x + s[0], 0.f); v0.y = fmaxf(v0.y + s[1], 0.f);
        v0.z = fmaxf(v0.z + s[2], 0.f); v0.w = fmaxf(v0.w + s[3], 0.f);
        v1.x = fmaxf(v1.x + s[4], 0.f); v1.y = fmaxf(v1.y + s[5], 0.f);
        v1.z = fmaxf(v1.z + s[6], 0.f); v1.w = fmaxf(v1.w + s[7], 0.f);
        *o0 = v0; *o1 = v1;
    }
}

// ---------------- fallback (atomic path, small ws) ----------------
__global__ __launch_bounds__(128) void k_self_old(const float* __restrict__ x,
                                                  const float* __restrict__ sw,
                                                  const float* __restrict__ bias,
                                                  float* __restrict__ out) {
    __shared__ float s_x[8][IN_DIM];
    int t = threadIdx.x;
    int n0 = blockIdx.x * 8;
    for (int i = t; i < 8 * IN_DIM; i += 128) {
        int r = i >> 7, j = i & 127;
        s_x[r][j] = x[(size_t)(n0 + r) * IN_DIM + j];
    }
    __syncthreads();
    float acc[8] = {0.f,0.f,0.f,0.f,0.f,0.f,0.f,0.f};
    for (int k = 0; k < IN_DIM; ++k) {
        float w = sw[k * OUT_DIM + t];
        #pragma unroll
        for (int i = 0; i < 8; ++i) acc[i] += s_x[i][k] * w;
    }
    float b = bias[t];
    #pragma unroll
    for (int i = 0; i < 8; ++i)
        out[(size_t)(n0 + i) * OUT_DIM + t] = acc[i] + b;
}

__global__ __launch_bounds__(256) void k_hist_rel(const int* __restrict__ etype,
                                                  int* __restrict__ counts_rel) {
    __shared__ int bins[N_REL];
    int t = threadIdx.x;
    if (t < N_REL) bins[t] = 0;
    __syncthreads();
    int e = blockIdx.x * 256 + t;
    if (e < N_EDGES) atomicAdd(&bins[etype[e]], 1);
    __syncthreads();
    if (t < N_REL && bins[t]) atomicAdd(&counts_rel[t], bins[t]);
}

__global__ void k_scan_rel(const int* __restrict__ counts, int* __restrict__ cursor) {
    if (threadIdx.x == 0) {
        int s = 0;
        for (int r = 0; r < N_REL; ++r) { cursor[r] = s; s += counts[r]; }
    }
}

__global__ __launch_bounds__(256) void k_scatter_rel(const int* __restrict__ etype,
                                                     int* __restrict__ cursor,
                                                     int* __restrict__ sorted) {
    __shared__ int bins[N_REL];
    __shared__ int base[N_REL];
    int t = threadIdx.x;
    if (t < N_REL) bins[t] = 0;
    __syncthreads();
    int e = blockIdx.x * 256 + t;
    int rel = 0;
    bool valid = (e < N_EDGES);
    if (valid) { rel = etype[e]; atomicAdd(&bins[rel], 1); }
    __syncthreads();
    if (t < N_REL) {
        base[t] = bins[t] ? atomicAdd(&cursor[t], bins[t]) : 0;
        bins[t] = 0;
    }
    __syncthreads();
    if (valid) {
        int p = atomicAdd(&bins[rel], 1);
        sorted[base[rel] + p] = e;
    }
}

__global__ __launch_bounds__(256) void k_edge_atomic(const float* __restrict__ x,
                                              const float* __restrict__ rw,
                                              const int* __restrict__ src,
                                              const int* __restrict__ dst,
                                              const int* __restrict__ etype,
                                              const int* __restrict__ sorted,
                                              float* __restrict__ out) {
    __shared__ int s_src[EPB], s_dst[EPB], s_rel[EPB];
    __shared__ float s_x[EPB][IN_DIM];
    int t = threadIdx.x;
    int e0 = blockIdx.x * EPB;
    if (t < EPB) {
        int eid = sorted[e0 + t];
        s_src[t] = src[eid]; s_dst[t] = dst[eid]; s_rel[t] = etype[eid];
    }
    __syncthreads();
    for (int i = t; i < EPB * IN_DIM; i += 256) {
        int e = i >> 7, j = i & 127;
        s_x[e][j] = x[(size_t)s_src[e] * IN_DIM + j];
    }
    int rel0 = s_rel[0];
    bool uni = true;
    for (int i = 1; i < EPB; ++i) uni &= (s_rel[i] == rel0);
    __syncthreads();
    int cg = t & 31, eg = t >> 5;
    for (int i = 0; i < 8; ++i) {
        int e = eg * 8 + i;
        int rel = uni ? rel0 : s_rel[e];
        const float4* Wr = (const float4*)(rw + (size_t)rel * IN_DIM * OUT_DIM);
        float a0=0.f, a1=0.f, a2=0.f, a3=0.f;
        for (int k = 0; k < 128; ++k) {
            float4 w = Wr[k * 32 + cg];
            float xv = s_x[e][k];
            a0 += xv * w.x; a1 += xv * w.y; a2 += xv * w.z; a3 += xv * w.w;
        }
        float* o = out + (size_t)s_dst[e] * OUT_DIM + cg * 4;
        atomicAdd(o + 0, a0); atomicAdd(o + 1, a1);
        atomicAdd(o + 2, a2); atomicAdd(o + 3, a3);
    }
}

__global__ void k_relu(float* __restrict__ out) {
    int i = blockIdx.x * blockDim.x + threadIdx.x;
    float4* o4 = (float4*)out;
    const int n4 = N_NODES * OUT_DIM / 4;
    if (i < n4) {
        float4 v = o4[i];
        v.x = fmaxf(v.x, 0.f); v.y = fmaxf(v.y, 0.f);
        v.z = fmaxf(v.z, 0.f); v.w = fmaxf(v.w, 0.f);
        o4[i] = v;
    }
}

extern "C" void kernel_launch(void* const* d_in, const int* in_sizes, int n_in,
                              void* d_out, int out_size, void* d_ws, size_t ws_size,
                              hipStream_t stream) {
    const float* x     = (const float*)d_in[0];
    const int*   eidx  = (const int*)d_in[1];
    const int*   etype = (const int*)d_in[2];
    const float* rw    = (const float*)d_in[3];
    const float* sw    = (const float*)d_in[4];
    const float* bias  = (const float*)d_in[5];
    float* out = (float*)d_out;
    const int* src = eidx;
    const int* dst = eidx + N_EDGES;

    // ---- workspace layout ----
    int* counts_rel = (int*)d_ws;                  // 16
    int* cursor_rel = counts_rel + 16;             // 16
    int* seg        = cursor_rel + 16;             // 32 (17 used)
    int* part       = seg + 32;                    // 512
    int* dst_count  = part + 512;                  // N
    int* row_ptr    = dst_count + N_NODES;         // N+1
    int* cursor_dst = row_ptr + N_NODES + 1;       // N
    int* sorted     = cursor_dst + N_NODES;        // E+PAD
    int* pos        = sorted + N_EDGES + PAD;      // E+PAD
    size_t off = (((char*)(pos + N_EDGES + PAD) - (char*)d_ws) + 255) & ~(size_t)255;
    u16* xb   = (u16*)((char*)d_ws + off);         // N*128 bf16
    u16* wtb  = xb + (size_t)N_NODES * 128;        // 17*16384 bf16 (transposed)
    u16* msgs = wtb + 17 * 16384;                  // (E+PAD)*128 bf16, dst-grouped
    size_t need = (size_t)((char*)(msgs + (size_t)(N_EDGES + PAD) * 128) - (char*)d_ws);

    const int EB = HIST_B;                         // 2500
    const int MB = (N_EDGES + PAD) / MEPB;         // 5016 blocks, 128 edges each

    if (ws_size >= need) {
        hipMemsetAsync(d_ws, 0, (size_t)(576 + N_NODES) * sizeof(int), stream);
        k_pre<<<CVT_XB + CVT_WB + EB, 256, 0, stream>>>(x, rw, sw, etype, dst,
                                                        xb, wtb, counts_rel, dst_count);
        k_scan1<<<NB_SCAN, 256, 0, stream>>>(dst_count, row_ptr, part);
        k_mid2<<<2, 512, 0, stream>>>(part, counts_rel, cursor_rel, seg, sorted);
        k_scan3<<<NB_SCAN, 256, 0, stream>>>(row_ptr, part, cursor_dst);
        k_scatter_pos<<<EB, 256, 0, stream>>>(etype, dst, cursor_rel, cursor_dst, sorted, pos);

        k_self_mfma<<<(N_NODES + 255) / 256, 256, 0, stream>>>(xb, wtb, bias, out);
        k_msg_mfma<<<MB, 256, 0, stream>>>(xb, wtb, src, etype, sorted, pos, msgs);
        k_gather<<<(N_NODES * 64 + 255) / 256, 256, 0, stream>>>(row_ptr, msgs, out);
    } else {
        // fallback: atomic path (needs only rel-sort scratch)
        hipMemsetAsync(counts_rel, 0, 16 * sizeof(int), stream);
        k_hist_rel<<<EB, 256, 0, stream>>>(etype, counts_rel);
        k_scan_rel<<<1, 64, 0, stream>>>(counts_rel, cursor_rel);
        k_scatter_rel<<<EB, 256, 0, stream>>>(etype, cursor_rel, sorted);
        k_self_old<<<N_NODES / 8, 128, 0, stream>>>(x, sw, bias, out);
        k_edge_atomic<<<N_EDGES / EPB, 256, 0, stream>>>(x, rw, src, dst, etype, sorted, out);
        k_relu<<<(N_NODES * OUT_DIM / 4 + 255) / 256, 256, 0, stream>>>(out);
    }
}

// Round 8
// 322.496 us; speedup vs baseline: 1.4700x; 1.1448x over previous
//
#include <hip/hip_runtime.h>

#define N_NODES 100000
#define N_EDGES 640000
#define IN_DIM  128
#define OUT_DIM 128
#define N_REL   16
#define EPB     64
#define MEPB    128                            // edges per block in k_msg
#define SELF_PAD 100096                        // self segment, 128-aligned (782*128)
#define MAX_SLOTS (SELF_PAD + N_EDGES + 2048)  // 742144 = 5798*128
#define SENT    (N_EDGES + N_NODES)            // pad sentinel
#define MSG_ROWS (N_EDGES + N_NODES + 128)     // +128 dump rows
#define NB_SCAN ((N_NODES + 255) / 256)
#define CVT_XB  (N_NODES * IN_DIM / 4 / 256)   // 12500 blocks for x
#define CVT_WB  (17 * 16384 / 256)             // 1088 blocks for W
#define HIST_B  ((N_EDGES + 255) / 256)        // 2500 hist blocks
#define SELF_B  (SELF_PAD / 256)               // 391 self-fill blocks

typedef unsigned short u16;
typedef unsigned int   u32;
typedef __attribute__((ext_vector_type(8))) short bf16x8;
typedef __attribute__((ext_vector_type(4))) float f32x4;

__device__ inline u16 f2bf(float f) {               // round-to-nearest-even
    u32 u = __builtin_bit_cast(u32, f);
    return (u16)((u + 0x7fffu + ((u >> 16) & 1u)) >> 16);
}
__device__ inline float bf2f(u16 s) {
    u32 u = ((u32)s) << 16;
    return __builtin_bit_cast(float, u);
}

// ---- fused pass 1: cvt-x, cvt-W (fragment layout), histograms, self-fill ----
// W fragment layout per relation: u16 offset (c*4+kk)*512 + (q*16+n)*8 + j
// holds Wt[row=c*16+n][k=kk*32+q*8+j]  (lane==q*16+n -> stride-1 LDS reads)
__global__ __launch_bounds__(256) void k_pre(const float* __restrict__ x,
                                             const float* __restrict__ rw,
                                             const float* __restrict__ sw,
                                             const int* __restrict__ etype,
                                             const int* __restrict__ dst,
                                             u16* __restrict__ xb,
                                             u16* __restrict__ wt,
                                             int* __restrict__ counts_rel,
                                             int* __restrict__ dst_count,
                                             int* __restrict__ sorted) {
    int b = blockIdx.x, t = threadIdx.x;
    if (b < CVT_XB) {
        int i = b * 256 + t;
        float4 v = ((const float4*)x)[i];
        ushort4 p; p.x = f2bf(v.x); p.y = f2bf(v.y); p.z = f2bf(v.z); p.w = f2bf(v.w);
        ((ushort4*)xb)[i] = p;
    } else if (b < CVT_XB + CVT_WB) {
        int i = (b - CVT_XB) * 256 + t;       // over 17*16384, exact
        int r = i >> 14, rem = i & 16383;
        int k = rem >> 7, np = rem & 127;     // input layout [r][k][n']
        float v = (r < 16) ? rw[i] : sw[rem];
        int c = np >> 4, nn = np & 15, kk = k >> 5, q = (k >> 3) & 3, j = k & 7;
        wt[(size_t)r * 16384 + (c * 4 + kk) * 512 + (q * 16 + nn) * 8 + j] = f2bf(v);
    } else if (b < CVT_XB + CVT_WB + HIST_B) {
        __shared__ int bins[N_REL];
        if (t < N_REL) bins[t] = 0;
        __syncthreads();
        int e = (b - CVT_XB - CVT_WB) * 256 + t;
        if (e < N_EDGES) {
            atomicAdd(&bins[etype[e]], 1);
            atomicAdd(&dst_count[dst[e]], 1);
        }
        __syncthreads();
        if (t < N_REL && bins[t]) atomicAdd(&counts_rel[t], bins[t]);
    } else {
        int i = (b - CVT_XB - CVT_WB - HIST_B) * 256 + t;   // < SELF_PAD
        sorted[i] = (i < N_NODES) ? (N_EDGES + i) : SENT;
    }
}

// ---------------- exclusive scan over (dst_count+1) -> row_ptr --------------
__global__ __launch_bounds__(256) void k_scan1(const int* __restrict__ dst_count,
                                               int* __restrict__ row_ptr,
                                               int* __restrict__ part) {
    __shared__ int buf[2][256];
    int t = threadIdx.x;
    int i = blockIdx.x * 256 + t;
    int v = (i < N_NODES) ? (dst_count[i] + 1) : 0;   // +1: self row per node
    buf[0][t] = v;
    __syncthreads();
    int cur = 0;
    #pragma unroll
    for (int off = 1; off < 256; off <<= 1) {
        int nxt = cur ^ 1;
        int s = buf[cur][t];
        if (t >= off) s += buf[cur][t - off];
        buf[nxt][t] = s;
        __syncthreads();
        cur = nxt;
    }
    int inc = buf[cur][t];
    if (i < N_NODES) row_ptr[i] = inc - v;
    if (t == 255) part[blockIdx.x] = inc;
}

// fused: block 0 = scan of part[]; block 1 = rel-scan (base SELF_PAD) + pads
__global__ __launch_bounds__(512) void k_mid2(int* __restrict__ part,
                                              const int* __restrict__ counts,
                                              int* __restrict__ cursor,
                                              int* __restrict__ seg,
                                              int* __restrict__ sorted) {
    int t = threadIdx.x;
    if (blockIdx.x == 0) {
        __shared__ int buf[2][512];
        int v = (t < NB_SCAN) ? part[t] : 0;
        buf[0][t] = v;
        __syncthreads();
        int cur = 0;
        #pragma unroll
        for (int off = 1; off < 512; off <<= 1) {
            int nxt = cur ^ 1;
            int s = buf[cur][t];
            if (t >= off) s += buf[cur][t - off];
            buf[nxt][t] = s;
            __syncthreads();
            cur = nxt;
        }
        int inc = buf[cur][t];
        if (t < NB_SCAN) part[t] = inc - v;
    } else {
        __shared__ int s_seg[N_REL + 1];
        if (t == 0) {
            int s = SELF_PAD;
            for (int r = 0; r < N_REL; ++r) {
                cursor[r] = s; seg[r] = s; s_seg[r] = s;
                s += (counts[r] + 127) & ~127;   // 128-align: k_msg blocks rel-uniform
            }
            seg[N_REL] = s; s_seg[N_REL] = s;
        }
        __syncthreads();
        for (int r = 0; r < N_REL; ++r) {
            int b = s_seg[r] + counts[r], e2 = s_seg[r + 1];
            if (b + t < e2) sorted[b + t] = SENT;   // pad < 128 per segment
        }
        for (int i = s_seg[N_REL] + t; i < MAX_SLOTS; i += 512)
            sorted[i] = SENT;
    }
}

__global__ __launch_bounds__(256) void k_scan3(int* __restrict__ row_ptr,
                                               const int* __restrict__ part,
                                               int* __restrict__ cursor_dst) {
    int t = threadIdx.x;
    int i = blockIdx.x * 256 + t;
    if (i < N_NODES) {
        int r = row_ptr[i] + part[blockIdx.x];
        row_ptr[i] = r;
        cursor_dst[i] = r + 1;          // slot r is the self row; edges start at r+1
    }
    if (i == 0) row_ptr[N_NODES] = N_EDGES + N_NODES;
}

// relation counting-sort (slots only; dst positions assigned inside k_msg)
__global__ __launch_bounds__(256) void k_scatter_rel(const int* __restrict__ etype,
                                                     int* __restrict__ cursor,
                                                     int* __restrict__ sorted) {
    __shared__ int bins[N_REL];
    __shared__ int base[N_REL];
    int t = threadIdx.x;
    if (t < N_REL) bins[t] = 0;
    __syncthreads();
    int e = blockIdx.x * 256 + t;
    int rel = 0;
    bool valid = (e < N_EDGES);
    if (valid) { rel = etype[e]; atomicAdd(&bins[rel], 1); }
    __syncthreads();
    if (t < N_REL) {
        base[t] = bins[t] ? atomicAdd(&cursor[t], bins[t]) : 0;
        bins[t] = 0;
    }
    __syncthreads();
    if (valid) {
        int p = atomicAdd(&bins[rel], 1);
        sorted[base[rel] + p] = e;
    }
}

// ---------------- phase 1 (MFMA): W in LDS (fragment order), 128 edges/block
// msg row layout: elem = q*32 + c*4 + r  <->  out col = c*16 + q*4 + r.
__global__ __launch_bounds__(256, 4) void k_msg_mfma(const u16* __restrict__ xb,
                                                     const u16* __restrict__ wt,
                                                     const int* __restrict__ src,
                                                     const int* __restrict__ etype,
                                                     const int* __restrict__ dst,
                                                     const int* __restrict__ sorted,
                                                     const int* __restrict__ row_ptr,
                                                     int* __restrict__ cursor_dst,
                                                     u16* __restrict__ msgs) {
    __shared__ u16 s_w[128 * 128];               // 32 KB, fragment order
    __shared__ int s_src[MEPB], s_pos[MEPB];
    int t = threadIdx.x;
    int e0 = blockIdx.x * MEPB;

    int ee0 = sorted[e0];                        // block-uniform relation
    int relb = (ee0 < N_EDGES) ? etype[ee0] : N_REL;
    const uint4* wsrc = (const uint4*)(wt + (size_t)relb * 16384);
    for (int i = t; i < 2048; i += 256)          // coalesced, conflict-free
        *(uint4*)&s_w[i * 8] = wsrc[i];
    if (t < MEPB) {
        int eid = sorted[e0 + t];
        int sv, pv;
        if (eid < N_EDGES) {
            sv = src[eid];
            pv = atomicAdd(&cursor_dst[dst[eid]], 1);
        } else if (eid < SENT) {
            sv = eid - N_EDGES;                  // self edge
            pv = row_ptr[sv];
        } else {
            sv = 0;
            pv = SENT + ((e0 + t) & 127);        // dump rows; races OK
        }
        s_src[t] = sv; s_pos[t] = pv;
    }
    __syncthreads();

    int wv = t >> 6, lane = t & 63;
    int n = lane & 15, q = lane >> 4;
    int eb = wv * 32;

    bf16x8 bx[2][4];
    int p[2];
    #pragma unroll
    for (int g = 0; g < 2; ++g) {
        int en = eb + g * 16 + n;
        const u16* xrow = xb + (size_t)s_src[en] * 128 + q * 8;
        p[g] = s_pos[en];
        #pragma unroll
        for (int kk = 0; kk < 4; ++kk)
            bx[g][kk] = *(const bf16x8*)(xrow + kk * 32);
    }

    uint4 uv[2][4];
    #pragma unroll
    for (int c = 0; c < 8; ++c) {
        bf16x8 aw[4];
        #pragma unroll
        for (int kk = 0; kk < 4; ++kk)           // addr = lane*16B: stride-1 b128
            aw[kk] = *(const bf16x8*)&s_w[(c * 4 + kk) * 512 + lane * 8];
        #pragma unroll
        for (int g = 0; g < 2; ++g) {
            f32x4 acc = {0.f, 0.f, 0.f, 0.f};
            #pragma unroll
            for (int kk = 0; kk < 4; ++kk)
                acc = __builtin_amdgcn_mfma_f32_16x16x32_bf16(aw[kk], bx[g][kk], acc, 0, 0, 0);
            u32 lo = (u32)f2bf(acc[0]) | ((u32)f2bf(acc[1]) << 16);
            u32 hi = (u32)f2bf(acc[2]) | ((u32)f2bf(acc[3]) << 16);
            if ((c & 1) == 0) { uv[g][c >> 1].x = lo; uv[g][c >> 1].y = hi; }
            else              { uv[g][c >> 1].z = lo; uv[g][c >> 1].w = hi; }
        }
    }
    #pragma unroll
    for (int g = 0; g < 2; ++g) {
        u32* mrow = (u32*)(msgs + (size_t)p[g] * 128 + q * 32);  // contiguous 64B
        #pragma unroll
        for (int j = 0; j < 4; ++j)
            *(uint4*)(mrow + j * 4) = uv[g][j];
    }
}

// ---------------- phase 2: per-node gather (+bias,+relu), pure write --------
__global__ __launch_bounds__(256) void k_gather(const int* __restrict__ row_ptr,
                                                const u16* __restrict__ msgs,
                                                const float* __restrict__ bias,
                                                float* __restrict__ out) {
    int wid  = (blockIdx.x * 256 + threadIdx.x) >> 6;
    int lane = threadIdx.x & 63;
    if (wid >= N_NODES) return;
    int r0 = row_ptr[wid], r1 = row_ptr[wid + 1];
    int h = lane & 15, quarter = lane >> 4;
    const uint4* m = (const uint4*)msgs;          // 16B units; row = 16 units
    float s[8] = {0.f,0.f,0.f,0.f,0.f,0.f,0.f,0.f};
    for (int i = r0 + quarter; i < r1; i += 4) {
        uint4 v = m[(size_t)i * 16 + h];
        s[0] += bf2f((u16)(v.x & 0xffffu)); s[1] += bf2f((u16)(v.x >> 16));
        s[2] += bf2f((u16)(v.y & 0xffffu)); s[3] += bf2f((u16)(v.y >> 16));
        s[4] += bf2f((u16)(v.z & 0xffffu)); s[5] += bf2f((u16)(v.z >> 16));
        s[6] += bf2f((u16)(v.w & 0xffffu)); s[7] += bf2f((u16)(v.w >> 16));
    }
    #pragma unroll
    for (int j = 0; j < 8; ++j) {
        s[j] += __shfl_xor(s[j], 16);
        s[j] += __shfl_xor(s[j], 32);
    }
    if (quarter == 0) {
        int c0 = (2 * h) & 7, c1 = (2 * h + 1) & 7, qq = h >> 2;
        float4 b0 = *(const float4*)&bias[c0 * 16 + qq * 4];
        float4 b1 = *(const float4*)&bias[c1 * 16 + qq * 4];
        float* ob = out + (size_t)wid * 128;
        float4 v0, v1;
        v0.x = fmaxf(s[0] + b0.x, 0.f); v0.y = fmaxf(s[1] + b0.y, 0.f);
        v0.z = fmaxf(s[2] + b0.z, 0.f); v0.w = fmaxf(s[3] + b0.w, 0.f);
        v1.x = fmaxf(s[4] + b1.x, 0.f); v1.y = fmaxf(s[5] + b1.y, 0.f);
        v1.z = fmaxf(s[6] + b1.z, 0.f); v1.w = fmaxf(s[7] + b1.w, 0.f);
        *(float4*)(ob + c0 * 16 + qq * 4) = v0;
        *(float4*)(ob + c1 * 16 + qq * 4) = v1;
    }
}

// ---------------- fallback (atomic path, small ws) ----------------
__global__ __launch_bounds__(128) void k_self_old(const float* __restrict__ x,
                                                  const float* __restrict__ sw,
                                                  const float* __restrict__ bias,
                                                  float* __restrict__ out) {
    __shared__ float s_x[8][IN_DIM];
    int t = threadIdx.x;
    int n0 = blockIdx.x * 8;
    for (int i = t; i < 8 * IN_DIM; i += 128) {
        int r = i >> 7, j = i & 127;
        s_x[r][j] = x[(size_t)(n0 + r) * IN_DIM + j];
    }
    __syncthreads();
    float acc[8] = {0.f,0.f,0.f,0.f,0.f,0.f,0.f,0.f};
    for (int k = 0; k < IN_DIM; ++k) {
        float w = sw[k * OUT_DIM + t];
        #pragma unroll
        for (int i = 0; i < 8; ++i) acc[i] += s_x[i][k] * w;
    }
    float b = bias[t];
    #pragma unroll
    for (int i = 0; i < 8; ++i)
        out[(size_t)(n0 + i) * OUT_DIM + t] = acc[i] + b;
}

__global__ __launch_bounds__(256) void k_hist_rel(const int* __restrict__ etype,
                                                  int* __restrict__ counts_rel) {
    __shared__ int bins[N_REL];
    int t = threadIdx.x;
    if (t < N_REL) bins[t] = 0;
    __syncthreads();
    int e = blockIdx.x * 256 + t;
    if (e < N_EDGES) atomicAdd(&bins[etype[e]], 1);
    __syncthreads();
    if (t < N_REL && bins[t]) atomicAdd(&counts_rel[t], bins[t]);
}

__global__ void k_scan_rel(const int* __restrict__ counts, int* __restrict__ cursor) {
    if (threadIdx.x == 0) {
        int s = 0;
        for (int r = 0; r < N_REL; ++r) { cursor[r] = s; s += counts[r]; }
    }
}

__global__ __launch_bounds__(256) void k_edge_atomic(const float* __restrict__ x,
                                              const float* __restrict__ rw,
                                              const int* __restrict__ src,
                                              const int* __restrict__ dst,
                                              const int* __restrict__ etype,
                                              const int* __restrict__ sorted,
                                              float* __restrict__ out) {
    __shared__ int s_src[EPB], s_dst[EPB], s_rel[EPB];
    __shared__ float s_x[EPB][IN_DIM];
    int t = threadIdx.x;
    int e0 = blockIdx.x * EPB;
    if (t < EPB) {
        int eid = sorted[e0 + t];
        s_src[t] = src[eid]; s_dst[t] = dst[eid]; s_rel[t] = etype[eid];
    }
    __syncthreads();
    for (int i = t; i < EPB * IN_DIM; i += 256) {
        int e = i >> 7, j = i & 127;
        s_x[e][j] = x[(size_t)s_src[e] * IN_DIM + j];
    }
    int rel0 = s_rel[0];
    bool uni = true;
    for (int i = 1; i < EPB; ++i) uni &= (s_rel[i] == rel0);
    __syncthreads();
    int cg = t & 31, eg = t >> 5;
    for (int i = 0; i < 8; ++i) {
        int e = eg * 8 + i;
        int rel = uni ? rel0 : s_rel[e];
        const float4* Wr = (const float4*)(rw + (size_t)rel * IN_DIM * OUT_DIM);
        float a0=0.f, a1=0.f, a2=0.f, a3=0.f;
        for (int k = 0; k < 128; ++k) {
            float4 w = Wr[k * 32 + cg];
            float xv = s_x[e][k];
            a0 += xv * w.x; a1 += xv * w.y; a2 += xv * w.z; a3 += xv * w.w;
        }
        float* o = out + (size_t)s_dst[e] * OUT_DIM + cg * 4;
        atomicAdd(o + 0, a0); atomicAdd(o + 1, a1);
        atomicAdd(o + 2, a2); atomicAdd(o + 3, a3);
    }
}

__global__ void k_relu(float* __restrict__ out) {
    int i = blockIdx.x * blockDim.x + threadIdx.x;
    float4* o4 = (float4*)out;
    const int n4 = N_NODES * OUT_DIM / 4;
    if (i < n4) {
        float4 v = o4[i];
        v.x = fmaxf(v.x, 0.f); v.y = fmaxf(v.y, 0.f);
        v.z = fmaxf(v.z, 0.f); v.w = fmaxf(v.w, 0.f);
        o4[i] = v;
    }
}

extern "C" void kernel_launch(void* const* d_in, const int* in_sizes, int n_in,
                              void* d_out, int out_size, void* d_ws, size_t ws_size,
                              hipStream_t stream) {
    const float* x     = (const float*)d_in[0];
    const int*   eidx  = (const int*)d_in[1];
    const int*   etype = (const int*)d_in[2];
    const float* rw    = (const float*)d_in[3];
    const float* sw    = (const float*)d_in[4];
    const float* bias  = (const float*)d_in[5];
    float* out = (float*)d_out;
    const int* src = eidx;
    const int* dst = eidx + N_EDGES;

    // ---- workspace layout ----
    int* counts_rel = (int*)d_ws;                  // 16
    int* cursor_rel = counts_rel + 16;             // 16
    int* seg        = cursor_rel + 16;             // 32 (17 used)
    int* part       = seg + 32;                    // 512
    int* dst_count  = part + 512;                  // N
    int* row_ptr    = dst_count + N_NODES;         // N+1
    int* cursor_dst = row_ptr + N_NODES + 1;       // N
    int* sorted     = cursor_dst + N_NODES;        // MAX_SLOTS
    size_t off = (((char*)(sorted + MAX_SLOTS) - (char*)d_ws) + 255) & ~(size_t)255;
    u16* xb   = (u16*)((char*)d_ws + off);         // N*128 bf16
    u16* wtb  = xb + (size_t)N_NODES * 128;        // 17*16384 bf16 (fragment order)
    u16* msgs = wtb + 17 * 16384;                  // MSG_ROWS*128 bf16, dst-grouped
    size_t need = (size_t)((char*)(msgs + (size_t)MSG_ROWS * 128) - (char*)d_ws);

    const int MB = MAX_SLOTS / MEPB;               // 5798 blocks

    if (ws_size >= need) {
        hipMemsetAsync(d_ws, 0, (size_t)(576 + N_NODES) * sizeof(int), stream);
        k_pre<<<CVT_XB + CVT_WB + HIST_B + SELF_B, 256, 0, stream>>>(
            x, rw, sw, etype, dst, xb, wtb, counts_rel, dst_count, sorted);
        k_scan1<<<NB_SCAN, 256, 0, stream>>>(dst_count, row_ptr, part);
        k_mid2<<<2, 512, 0, stream>>>(part, counts_rel, cursor_rel, seg, sorted);
        k_scan3<<<NB_SCAN, 256, 0, stream>>>(row_ptr, part, cursor_dst);
        k_scatter_rel<<<HIST_B, 256, 0, stream>>>(etype, cursor_rel, sorted);

        k_msg_mfma<<<MB, 256, 0, stream>>>(xb, wtb, src, etype, dst, sorted,
                                           row_ptr, cursor_dst, msgs);
        k_gather<<<(N_NODES * 64 + 255) / 256, 256, 0, stream>>>(row_ptr, msgs, bias, out);
    } else {
        // fallback: atomic path (needs only rel-sort scratch)
        hipMemsetAsync(counts_rel, 0, 16 * sizeof(int), stream);
        k_hist_rel<<<HIST_B, 256, 0, stream>>>(etype, counts_rel);
        k_scan_rel<<<1, 64, 0, stream>>>(counts_rel, cursor_rel);
        k_scatter_rel<<<HIST_B, 256, 0, stream>>>(etype, cursor_rel, sorted);
        k_self_old<<<N_NODES / 8, 128, 0, stream>>>(x, sw, bias, out);
        k_edge_atomic<<<N_EDGES / EPB, 256, 0, stream>>>(x, rw, src, dst, etype, sorted, out);
        k_relu<<<(N_NODES * OUT_DIM / 4 + 255) / 256, 256, 0, stream>>>(out);
    }
}